// Round 3
// baseline (195.856 us; speedup 1.0000x reference)
//
#include <hip/hip_runtime.h>
#include <hip/hip_fp8.h>

#define N_NODES 50000
#define N_EDGES 800000
#define IN_C    128
#define HID_C   128
#define OUT_C   64

#define CAPN        64          // per-node edge capacity (mean deg 16, Poisson tail @64 ~ 1e-18)
#define SCAT_BLOCKS 256         // scatter blocks inside fused launch
#define GEMM1_BLOCKS 782        // ceil(50000/64)

typedef unsigned int   uint32;
typedef unsigned short ushort16;
typedef unsigned char  uchar8;
typedef __attribute__((ext_vector_type(8))) short short8;
typedef __attribute__((ext_vector_type(4))) float f32x4;

__device__ __forceinline__ ushort16 f2bf(float f) {
    uint32 u = __float_as_uint(f);
    u += 0x7FFFu + ((u >> 16) & 1u);        // RNE
    return (ushort16)(u >> 16);
}
__device__ __forceinline__ float bf_lo(uint32 h) { return __uint_as_float(h << 16); }
__device__ __forceinline__ float bf_hi(uint32 h) { return __uint_as_float(h & 0xFFFF0000u); }

__device__ __forceinline__ ushort16 f2h_bits(float f) {
    union { _Float16 h; ushort16 u; } cv;
    cv.h = (_Float16)f;
    return cv.u;
}
__device__ __forceinline__ float h_bits2f(uint32 bits) {
    union { ushort16 u; _Float16 h; } cv;
    cv.u = (ushort16)bits;
    return (float)cv.h;
}
__device__ __forceinline__ uchar8 f2fp8(float f) {
    __hip_fp8_e4m3 t(f);                    // OCP e4m3fn, RNE-saturating
    return *reinterpret_cast<unsigned char*>(&t);
}
__device__ __forceinline__ float fp82f(uchar8 b) {
    __hip_fp8_e4m3 t;
    *reinterpret_cast<unsigned char*>(&t) = b;
    return (float)t;
}

// ---- W pre-transpose (bf16) + per-node cursor zeroing -----------------------
__global__ __launch_bounds__(256) void prep_w_kernel(const float* __restrict__ W1,
                                                     const float* __restrict__ W2,
                                                     ushort16* __restrict__ W1t,
                                                     ushort16* __restrict__ W2t,
                                                     int* __restrict__ cursorN) {
    int gid = blockIdx.x * 256 + threadIdx.x;          // 0..24575
    for (int j = gid; j < N_NODES; j += 96 * 256) cursorN[j] = 0;
    if (gid < 128 * 128) {
        int n = gid / 128, k = gid % 128;
        W1t[gid] = f2bf(W1[k * 128 + n]);
    }
    int j = gid - 128 * 128;
    if (j >= 0 && j < 64 * 128) {
        int n = j / 128, k = j % 128;
        W2t[j] = f2bf(W2[k * 64 + n]);
    }
}

// ---- Fused launch: [scatter blocks] + [gemm1 blocks] (independent work) -----
// scatter: edges -> pairs[dst*CAPN + pos], pos via one global atomic per edge.
// gemm1:   H1(bf16) = x @ W1 via MFMA.
__global__ __launch_bounds__(256) void gemm1_scatter_kernel(const float* __restrict__ x,
                                                            const ushort16* __restrict__ W1t,
                                                            uint32* __restrict__ H1,
                                                            const int* __restrict__ ei,
                                                            const float* __restrict__ ew,
                                                            int* __restrict__ cursorN,
                                                            uint32* __restrict__ pairs) {
    __shared__ ushort16 As[64][136];       // +8 pad breaks 16-way bank aliasing
    __shared__ ushort16 Ws[128][136];

    if (blockIdx.x < SCAT_BLOCKS) {
        // ---------------- scatter path (memory-latency bound, no LDS) --------
        int t0 = blockIdx.x * 256 + threadIdx.x;
        for (int e = t0; e < N_EDGES; e += SCAT_BLOCKS * 256) {
            int dst = ei[N_EDGES + e];
            int src = ei[e];
            float w = ew[e];
            int pos = atomicAdd(&cursorN[dst], 1);
            if (pos < CAPN)
                pairs[dst * CAPN + pos] = ((uint32)f2h_bits(w) << 16) | (uint32)src;
        }
        return;
    }

    // ---------------- gemm1 path (MFMA) ----------------------------------
    const int tid  = threadIdx.x;
    const int wave = tid >> 6;
    const int lane = tid & 63;
    const int quad = lane >> 4;
    const int m    = lane & 15;
    const int blockRow = (blockIdx.x - SCAT_BLOCKS) * 64;

#pragma unroll
    for (int p = 0; p < 8; p++) {
        int u = tid + 256 * p;
        int row = u / 16, c8 = u % 16;
        uint4 v = ((const uint4*)W1t)[u];
        *((uint4*)&Ws[row][c8 * 8]) = v;
    }
#pragma unroll
    for (int p = 0; p < 8; p++) {
        int u = tid + 256 * p;
        int row = u / 32, c4 = u % 32;
        int gr = blockRow + row; if (gr > N_NODES - 1) gr = N_NODES - 1;
        float4 v = ((const float4*)x)[gr * 32 + c4];
        ushort4 s;
        s.x = f2bf(v.x); s.y = f2bf(v.y); s.z = f2bf(v.z); s.w = f2bf(v.w);
        *((ushort4*)&As[row][c4 * 4]) = s;
    }
    __syncthreads();

    f32x4 acc[8];
#pragma unroll
    for (int nt = 0; nt < 8; nt++) acc[nt] = (f32x4){0.f, 0.f, 0.f, 0.f};

#pragma unroll
    for (int kc = 0; kc < 128; kc += 32) {
        short8 a = *((const short8*)&As[wave * 16 + m][kc + quad * 8]);
#pragma unroll
        for (int nt = 0; nt < 8; nt++) {
            short8 b = *((const short8*)&Ws[nt * 16 + m][kc + quad * 8]);
            acc[nt] = __builtin_amdgcn_mfma_f32_16x16x32_bf16(a, b, acc[nt], 0, 0, 0);
        }
    }

    __syncthreads();
#pragma unroll
    for (int nt = 0; nt < 8; nt++)
#pragma unroll
        for (int r = 0; r < 4; r++)
            As[wave * 16 + quad * 4 + r][nt * 16 + m] = f2bf(acc[nt][r]);
    __syncthreads();
#pragma unroll
    for (int p = 0; p < 4; p++) {
        int u = tid + 256 * p;
        int row = u / 16, c8 = u % 16;
        int gr = blockRow + row;
        if (gr < N_NODES)
            ((uint4*)H1)[gr * 16 + c8] = *((const uint4*)&As[row][c8 * 8]);
    }
}

// ---------------- MFMA GEMM (gemm2): C[M,64] = A[M,128] * W[128,64] ----------
template<int NT, bool ABF16, bool OUTFP8>
__global__ __launch_bounds__(256) void mfma_gemm_kernel(const void* __restrict__ Aptr,
                                                        const ushort16* __restrict__ Wt,
                                                        void* __restrict__ Cout, int M) {
    constexpr int N = NT * 16;
    __shared__ ushort16 As[64][136];
    __shared__ ushort16 Ws[N][136];

    const int tid  = threadIdx.x;
    const int wave = tid >> 6;
    const int lane = tid & 63;
    const int quad = lane >> 4;
    const int m    = lane & 15;
    const int blockRow = blockIdx.x * 64;

#pragma unroll
    for (int p = 0; p < N * 16 / 256; p++) {
        int u = tid + 256 * p;
        int row = u / 16, c8 = u % 16;
        uint4 v = ((const uint4*)Wt)[u];
        *((uint4*)&Ws[row][c8 * 8]) = v;
    }
    if (ABF16) {
#pragma unroll
        for (int p = 0; p < 4; p++) {
            int u = tid + 256 * p;
            int row = u / 16, c8 = u % 16;
            int gr = blockRow + row; if (gr > M - 1) gr = M - 1;
            uint4 v = ((const uint4*)Aptr)[gr * 16 + c8];
            *((uint4*)&As[row][c8 * 8]) = v;
        }
    } else {
#pragma unroll
        for (int p = 0; p < 8; p++) {
            int u = tid + 256 * p;
            int row = u / 32, c4 = u % 32;
            int gr = blockRow + row; if (gr > M - 1) gr = M - 1;
            float4 v = ((const float4*)Aptr)[gr * 32 + c4];
            ushort4 s;
            s.x = f2bf(v.x); s.y = f2bf(v.y); s.z = f2bf(v.z); s.w = f2bf(v.w);
            *((ushort4*)&As[row][c4 * 4]) = s;
        }
    }
    __syncthreads();

    f32x4 acc[NT];
#pragma unroll
    for (int nt = 0; nt < NT; nt++) acc[nt] = (f32x4){0.f, 0.f, 0.f, 0.f};

#pragma unroll
    for (int kc = 0; kc < 128; kc += 32) {
        short8 a = *((const short8*)&As[wave * 16 + m][kc + quad * 8]);
#pragma unroll
        for (int nt = 0; nt < NT; nt++) {
            short8 b = *((const short8*)&Ws[nt * 16 + m][kc + quad * 8]);
            acc[nt] = __builtin_amdgcn_mfma_f32_16x16x32_bf16(a, b, acc[nt], 0, 0, 0);
        }
    }

    __syncthreads();
    if (OUTFP8) {
        uchar8* c8lds = (uchar8*)&As[0][0];
#pragma unroll
        for (int nt = 0; nt < NT; nt++)
#pragma unroll
            for (int r = 0; r < 4; r++)
                c8lds[(wave * 16 + quad * 4 + r) * N + nt * 16 + m] = f2fp8(acc[nt][r]);
        __syncthreads();
#pragma unroll
        for (int p = 0; p < 64 * N / 16 / 256; p++) {
            int u = tid + 256 * p;
            int row = u / (N / 16), c16 = u % (N / 16);
            int gr = blockRow + row;
            if (gr < M)
                ((uint4*)Cout)[gr * (N / 16) + c16] = *((const uint4*)&c8lds[row * N + c16 * 16]);
        }
    } else {
#pragma unroll
        for (int nt = 0; nt < NT; nt++)
#pragma unroll
            for (int r = 0; r < 4; r++)
                As[wave * 16 + quad * 4 + r][nt * 16 + m] = f2bf(acc[nt][r]);
        __syncthreads();
#pragma unroll
        for (int p = 0; p < 64 * N / 8 / 256; p++) {
            int u = tid + 256 * p;
            int row = u / (N / 8), c8 = u % (N / 8);
            int gr = blockRow + row;
            if (gr < M)
                ((uint4*)Cout)[gr * (N / 8) + c8] = *((const uint4*)&As[row][c8 * 8]);
        }
    }
}

// ---------------- Aggregations (wave = node, fixed-stride pair rows) ---------
__global__ __launch_bounds__(256) void agg1_kernel(const uint32* __restrict__ H1,
                                                   const int* __restrict__ cursorN,
                                                   const uint32* __restrict__ pairs,
                                                   const float* __restrict__ b1,
                                                   uint32* __restrict__ A1) {
    int node = blockIdx.x * 4 + (threadIdx.x >> 6);
    int lane = threadIdx.x & 63;
    if (node >= N_NODES) return;
    int cnt = cursorN[node]; if (cnt > CAPN) cnt = CAPN;
    const uint32* pr = pairs + node * CAPN;
    float2 acc = ((const float2*)b1)[lane];
    int i = 0;
    for (; i + 8 <= cnt; i += 8) {
        uint32 p[8], h[8];
#pragma unroll
        for (int j = 0; j < 8; j++) p[j] = pr[i + j];
#pragma unroll
        for (int j = 0; j < 8; j++) h[j] = H1[(p[j] & 0xFFFFu) * 64 + lane];
#pragma unroll
        for (int j = 0; j < 8; j++) {
            float w = h_bits2f(p[j] >> 16);
            acc.x += w * bf_lo(h[j]);
            acc.y += w * bf_hi(h[j]);
        }
    }
    for (; i < cnt; i++) {
        uint32 p = pr[i];
        uint32 h = H1[(p & 0xFFFFu) * 64 + lane];
        float  w = h_bits2f(p >> 16);
        acc.x += w * bf_lo(h);
        acc.y += w * bf_hi(h);
    }
    float rx = fmaxf(acc.x, 0.f), ry = fmaxf(acc.y, 0.f);
    A1[node * 64 + lane] = (uint32)f2bf(rx) | ((uint32)f2bf(ry) << 16);
}

// agg2: out[i](fp32) = b2 + sum_e H2[src_e]; H2 fp8 e4m3, 64 B/row (L2-resident)
__global__ __launch_bounds__(256) void agg2_kernel(const uchar8* __restrict__ H2,
                                                   const int* __restrict__ cursorN,
                                                   const uint32* __restrict__ pairs,
                                                   const float* __restrict__ b2,
                                                   float* __restrict__ out) {
    int node = blockIdx.x * 4 + (threadIdx.x >> 6);
    int lane = threadIdx.x & 63;
    if (node >= N_NODES) return;
    int cnt = cursorN[node]; if (cnt > CAPN) cnt = CAPN;
    const uint32* pr = pairs + node * CAPN;
    float acc = b2[lane];
    int i = 0;
    for (; i + 8 <= cnt; i += 8) {
        uint32 p[8];
        uchar8 v[8];
#pragma unroll
        for (int j = 0; j < 8; j++) p[j] = pr[i + j];
#pragma unroll
        for (int j = 0; j < 8; j++) v[j] = H2[(p[j] & 0xFFFFu) * 64 + lane];
#pragma unroll
        for (int j = 0; j < 8; j++) acc += fp82f(v[j]);
    }
    for (; i < cnt; i++)
        acc += fp82f(H2[(pr[i] & 0xFFFFu) * 64 + lane]);
    out[node * 64 + lane] = acc;
}

// ---------------- launch -----------------------------------------------------
extern "C" void kernel_launch(void* const* d_in, const int* in_sizes, int n_in,
                              void* d_out, int out_size, void* d_ws, size_t ws_size,
                              hipStream_t stream) {
    const float* x  = (const float*)d_in[0];
    const int*   ei = (const int*)  d_in[1];   // [2, E] int32
    const float* ew = (const float*)d_in[2];
    const float* W1 = (const float*)d_in[3];
    const float* b1 = (const float*)d_in[4];
    const float* W2 = (const float*)d_in[5];
    const float* b2 = (const float*)d_in[6];
    float* out = (float*)d_out;

    // workspace layout (u32 units)
    uint32* H1      = (uint32*)d_ws;                   // 50000*64  (bf16 [N][128])
    uint32* A1      = H1 + (size_t)N_NODES * 64;       // 50000*64  (bf16 [N][128])
    uint32* H2      = A1 + (size_t)N_NODES * 64;       // 50000*16  (fp8 [N][64])
    uint32* pairs   = H2 + (size_t)N_NODES * 16;       // 50000*64 (f16 w << 16 | src u16)
    ushort16* W1t   = (ushort16*)(pairs + (size_t)N_NODES * CAPN); // 128*128 bf16
    ushort16* W2t   = W1t + 128 * 128;                 // 64*128 bf16 transposed
    int* cursorN    = (int*)(W2t + 64 * 128);          // 50000

    const int nodeBlocks = (N_NODES + 3) / 4;       // 12500

    // W transposes (bf16) + zero per-node cursors
    prep_w_kernel<<<96, 256, 0, stream>>>(W1, W2, W1t, W2t, cursorN);

    // fused: scatter (blocks 0..255) || H1 = x @ W1 (blocks 256..1037)
    gemm1_scatter_kernel<<<SCAT_BLOCKS + GEMM1_BLOCKS, 256, 0, stream>>>(
        x, W1t, H1, ei, ew, cursorN, pairs);

    // A1(bf16) = relu(segment_sum(w * H1[src]) + b1)
    agg1_kernel<<<nodeBlocks, 256, 0, stream>>>(H1, cursorN, pairs, b1, A1);

    // H2(fp8) = A1 @ W2   [MFMA, bf16 A, fp8 out]
    mfma_gemm_kernel<4, true, true><<<GEMM1_BLOCKS, 256, 0, stream>>>(A1, W2t, H2, N_NODES);

    // out = segment_sum(H2[src]) + b2
    agg2_kernel<<<nodeBlocks, 256, 0, stream>>>((const uchar8*)H2, cursorN, pairs, b2, out);
}